// Round 15
// baseline (85.501 us; speedup 1.0000x reference)
//
#include <hip/hip_runtime.h>
#include <math.h>

#define NQ 14
#define DIM (1 << NQ)      // 16384 amplitudes
#define NT 1024            // 16 waves per block; 1 block/CU -> 4 waves/SIMD
#define TA 16              // amplitudes per thread (4-bit tile)
#define NW (NT / 64)
#define PDIM (DIM + DIM / 32)   // padded: one spare cf2 per 32

// ---- compile-time for ----
template <int J> struct IC { static constexpr int v = J; };
template <int N, typename F>
__device__ __forceinline__ void sfor(F&& f) {
    if constexpr (N > 0) { sfor<N - 1>(f); f(IC<N - 1>{}); }
}

// ---- complex amplitude as a 2-wide ext_vector (one 64-bit VGPR pair) ----
typedef float cf2 __attribute__((ext_vector_type(2)));

// ---- packed fp32 gate math (r14-verified: hand VOP3P asm; clang won't lower
// <2 x float> to v_pk_*). NEW: coefficients live as ONE (c,s) register pair;
// op_sel broadcasts c (lo) or s (hi) to both lanes -> half the coeff VGPRs,
// critical under the 64-VGPR clamp at NT=1024. ----
__device__ __forceinline__ cf2 pk_mul_c(cf2 cs, cf2 a) {          // c * a
    cf2 t;
    asm("v_pk_mul_f32 %0, %1, %2 op_sel:[0,0] op_sel_hi:[0,1]"
        : "=v"(t) : "v"(cs), "v"(a));
    return t;
}
__device__ __forceinline__ cf2 pk_mul_s(cf2 cs, cf2 a) {          // s * a
    cf2 t;
    asm("v_pk_mul_f32 %0, %1, %2 op_sel:[1,0] op_sel_hi:[1,1]"
        : "=v"(t) : "v"(cs), "v"(a));
    return t;
}
__device__ __forceinline__ cf2 pk_mul_s_swapneg(cf2 cs, cf2 a) {  // s * (a.y, -a.x)
    cf2 t;
    asm("v_pk_mul_f32 %0, %1, %2 op_sel:[1,1] op_sel_hi:[1,0] neg_hi:[0,1]"
        : "=v"(t) : "v"(cs), "v"(a));
    return t;
}
__device__ __forceinline__ cf2 pk_fma_c(cf2 cs, cf2 a, cf2 b) {   // c*a + b
    cf2 d;
    asm("v_pk_fma_f32 %0, %1, %2, %3 op_sel:[0,0,0] op_sel_hi:[0,1,1]"
        : "=v"(d) : "v"(cs), "v"(a), "v"(b));
    return d;
}
__device__ __forceinline__ cf2 pk_fma_s(cf2 cs, cf2 a, cf2 b) {   // s*a + b
    cf2 d;
    asm("v_pk_fma_f32 %0, %1, %2, %3 op_sel:[1,0,0] op_sel_hi:[1,1,1]"
        : "=v"(d) : "v"(cs), "v"(a), "v"(b));
    return d;
}
__device__ __forceinline__ cf2 pk_fma_c_nb(cf2 cs, cf2 a, cf2 b) { // c*a - b
    cf2 d;
    asm("v_pk_fma_f32 %0, %1, %2, %3 op_sel:[0,0,0] op_sel_hi:[0,1,1] neg_lo:[0,0,1] neg_hi:[0,0,1]"
        : "=v"(d) : "v"(cs), "v"(a), "v"(b));
    return d;
}

// ---- state: 16 INDEPENDENT cf2 SSA values (compile-time indexed).
// r8: mega-vector serializes loads. r10: computed (XOR) addresses spill.
// Independent cf2 + additive-pad immediate offsets = no spill (r11+). ----
struct St {
    cf2 a0, a1, a2, a3, a4, a5, a6, a7, a8, a9, a10, a11, a12, a13, a14, a15;
};
template <int J> __device__ __forceinline__ cf2& amp(St& s);
#define AMP_GET(J) template <> __device__ __forceinline__ cf2& amp<J>(St& s) { return s.a##J; }
AMP_GET(0)  AMP_GET(1)  AMP_GET(2)  AMP_GET(3)  AMP_GET(4)  AMP_GET(5)  AMP_GET(6)  AMP_GET(7)
AMP_GET(8)  AMP_GET(9)  AMP_GET(10) AMP_GET(11) AMP_GET(12) AMP_GET(13) AMP_GET(14) AMP_GET(15)

// ---- additive padded layout: phys(idx) = idx + (idx>>5); tile base bits and
// offset bits disjoint -> phys splits; every LDS access = base + const. ----
__host__ __device__ constexpr int pad(int idx) { return idx + (idx >> 5); }

template <int P0, int P1, int P2, int P3>
struct Tile4 {
    static constexpr int PMASK = (1 << P0) | (1 << P1) | (1 << P2) | (1 << P3);
    static __device__ __forceinline__ int base_idx(int t) {
        int idx = 0, tb = 0;
#pragma unroll
        for (int p = 0; p < NQ; ++p)
            if (!((PMASK >> p) & 1)) { idx |= ((t >> tb) & 1) << p; ++tb; }
        return idx;
    }
    static constexpr int off(int j) {
        return ((j & 1) << P0) | (((j >> 1) & 1) << P1) |
               (((j >> 2) & 1) << P2) | (((j >> 3) & 1) << P3);
    }
    static constexpr int poff(int j) { return pad(off(j)); }
};

// qubit q lives at bit position 13-q. 5 rounds/layer:
using TileR1 = Tile4<13, 12, 11, 10>;  // l0=q0, l1=q1, l2=q2, l3=q3
using TileR2 = Tile4<10, 9, 8, 7>;     // l0=q3, l1=q4, l2=q5, l3=q6
using TileR3 = Tile4<7, 6, 5, 4>;      // l0=q6, l1=q7, l2=q8, l3=q9
using TileR4 = Tile4<4, 3, 2, 1>;      // l0=q9, l1=q10, l2=q11, l3=q12
using TileR5 = Tile4<1, 0, 13, 12>;    // l0=q12, l1=q13, l2=q0, l3=q1

template <class T>
__device__ __forceinline__ void load_tile(const cf2* s, int pb, St& st) {
    sfor<TA>([&](auto jc) {
        constexpr int j = decltype(jc)::v;
        amp<j>(st) = s[pb + T::poff(j)];
    });
}
template <class T>
__device__ __forceinline__ void store_tile(cf2* s, int pb, St& st) {
    sfor<TA>([&](auto jc) {
        constexpr int j = decltype(jc)::v;
        s[pb + T::poff(j)] = amp<j>(st);
    });
}

// RY: [[c,-s],[s,c]]  — cs = (c,s) in one register pair
template <int LB>
__device__ __forceinline__ void g_ry(St& st, cf2 cs) {
    sfor<TA>([&](auto jc) {
        constexpr int j = decltype(jc)::v;
        if constexpr (!(j & (1 << LB))) {
            constexpr int k = j | (1 << LB);
            cf2 aj = amp<j>(st), ak = amp<k>(st);
            amp<j>(st) = pk_fma_c_nb(cs, aj, pk_mul_s(cs, ak));   // c*aj - s*ak
            amp<k>(st) = pk_fma_s(cs, aj, pk_mul_c(cs, ak));      // s*aj + c*ak
        }
    });
}
// RX: [[c,-is],[-is,c]]
template <int LB>
__device__ __forceinline__ void g_rx(St& st, cf2 cs) {
    sfor<TA>([&](auto jc) {
        constexpr int j = decltype(jc)::v;
        if constexpr (!(j & (1 << LB))) {
            constexpr int k = j | (1 << LB);
            cf2 aj = amp<j>(st), ak = amp<k>(st);
            amp<j>(st) = pk_fma_c(cs, aj, pk_mul_s_swapneg(cs, ak));
            amp<k>(st) = pk_fma_c(cs, ak, pk_mul_s_swapneg(cs, aj));
        }
    });
}
// CNOT control local LC, target local LT: pure SSA rename (free)
template <int LC, int LT>
__device__ __forceinline__ void g_cnot(St& st) {
    sfor<TA>([&](auto jc) {
        constexpr int j = decltype(jc)::v;
        if constexpr (((j >> LC) & 1) && !((j >> LT) & 1)) {
            constexpr int k = j | (1 << LT);
            cf2 t = amp<j>(st);
            amp<j>(st) = amp<k>(st);
            amp<k>(st) = t;
        }
    });
}

// Per layer, 5 rounds (ring CNOTs (q0,q1)..(q12,q13)(q13,q0)):
//  R1: RX q0-3 (l0-l3),  CNOT<0,1><1,2><2,3>  = (q0,q1)(q1,q2)(q2,q3)
//  R2: RX q4-6 (l1-l3),  CNOT<0,1><1,2><2,3>  = (q3,q4)(q4,q5)(q5,q6)
//  R3: RX q7-9,          CNOT = (q6,q7)(q7,q8)(q8,q9)
//  R4: RX q10-12,        CNOT = (q9,q10)(q10,q11)(q11,q12)
//  R5: RX q13 (l1),      CNOT<0,1>=(q12,q13), <1,2>=(q13,q0)
// Embedding RYs folded into layer-0's rounds (RY precedes RX per qubit).
__global__ void __launch_bounds__(NT) qsim_kernel(const float* __restrict__ x,
                                                  const float* __restrict__ w,
                                                  float* __restrict__ out) {
    __shared__ cf2 sSt[PDIM];            // ~132 KB padded
    __shared__ cf2 sCS[56];              // (cos,sin) pairs: [0..13]=RY embed, 14+l*14+q = RX
    __shared__ float sRed[NW][NQ];

    const int tid = threadIdx.x;
    const int b = blockIdx.x;

    if (tid < 14) {
        float th = tanhf(x[b * NQ + tid]) * 1.57079632679489662f;
        cf2 v; v.x = cosf(th); v.y = sinf(th);
        sCS[tid] = v;
    } else if (tid < 56) {
        float th = w[tid - 14] * 0.5f;
        cf2 v; v.x = cosf(th); v.y = sinf(th);
        sCS[tid] = v;
    }

    const int pb1 = pad(TileR1::base_idx(tid));
    const int pb2 = pad(TileR2::base_idx(tid));
    const int pb3 = pad(TileR3::base_idx(tid));
    const int pb4 = pad(TileR4::base_idx(tid));
    const int pb5 = pad(TileR5::base_idx(tid));

    __syncthreads();

    St st;

    // ================= layer 0 (embedding folded in) =================
    {   // R1: init |0..0> + RY q0-3 + RX q0-3 + CNOTs (no tile loads -> inline coeffs ok)
        sfor<TA>([&](auto jc) {
            constexpr int j = decltype(jc)::v;
            cf2 z; z.x = 0.f; z.y = 0.f;
            amp<j>(st) = z;
        });
        if (tid == 0) amp<0>(st).x = 1.f;
        g_ry<0>(st, sCS[0]); g_ry<1>(st, sCS[1]); g_ry<2>(st, sCS[2]); g_ry<3>(st, sCS[3]);
        g_rx<0>(st, sCS[14]); g_rx<1>(st, sCS[15]); g_rx<2>(st, sCS[16]); g_rx<3>(st, sCS[17]);
        g_cnot<0, 1>(st); g_cnot<1, 2>(st); g_cnot<2, 3>(st);
        store_tile<TileR1>(sSt, pb1, st);
    }
    __syncthreads();
    {   // R2: RY q4-6 + RX q4-6 + CNOT(q3,q4)(q4,q5)(q5,q6)
        cf2 y4 = sCS[4], y5 = sCS[5], y6 = sCS[6];
        cf2 x4 = sCS[18], x5 = sCS[19], x6 = sCS[20];
        load_tile<TileR2>(sSt, pb2, st);
        g_ry<1>(st, y4); g_ry<2>(st, y5); g_ry<3>(st, y6);
        g_rx<1>(st, x4); g_rx<2>(st, x5); g_rx<3>(st, x6);
        g_cnot<0, 1>(st); g_cnot<1, 2>(st); g_cnot<2, 3>(st);
        store_tile<TileR2>(sSt, pb2, st);
    }
    __syncthreads();
    {   // R3: RY q7-9 + RX q7-9 + CNOT(q6,q7)(q7,q8)(q8,q9)
        cf2 y7 = sCS[7], y8 = sCS[8], y9 = sCS[9];
        cf2 x7 = sCS[21], x8 = sCS[22], x9 = sCS[23];
        load_tile<TileR3>(sSt, pb3, st);
        g_ry<1>(st, y7); g_ry<2>(st, y8); g_ry<3>(st, y9);
        g_rx<1>(st, x7); g_rx<2>(st, x8); g_rx<3>(st, x9);
        g_cnot<0, 1>(st); g_cnot<1, 2>(st); g_cnot<2, 3>(st);
        store_tile<TileR3>(sSt, pb3, st);
    }
    __syncthreads();
    {   // R4: RY q10-12 + RX q10-12 + CNOT(q9,q10)(q10,q11)(q11,q12)
        cf2 yA = sCS[10], yB = sCS[11], yC = sCS[12];
        cf2 xA = sCS[24], xB = sCS[25], xC = sCS[26];
        load_tile<TileR4>(sSt, pb4, st);
        g_ry<1>(st, yA); g_ry<2>(st, yB); g_ry<3>(st, yC);
        g_rx<1>(st, xA); g_rx<2>(st, xB); g_rx<3>(st, xC);
        g_cnot<0, 1>(st); g_cnot<1, 2>(st); g_cnot<2, 3>(st);
        store_tile<TileR4>(sSt, pb4, st);
    }
    __syncthreads();
    {   // R5: RY q13 + RX q13 + CNOT(q12,q13)(q13,q0)
        cf2 yD = sCS[13], xD = sCS[27];
        load_tile<TileR5>(sSt, pb5, st);
        g_ry<1>(st, yD);
        g_rx<1>(st, xD);
        g_cnot<0, 1>(st); g_cnot<1, 2>(st);
        store_tile<TileR5>(sSt, pb5, st);
    }
    __syncthreads();

    // ================= layers 1,2 =================
#pragma unroll 1
    for (int l = 1; l < 3; ++l) {
        const int s0 = 14 + l * NQ;
        {   // R1
            cf2 c0 = sCS[s0 + 0], c1 = sCS[s0 + 1], c2 = sCS[s0 + 2], c3 = sCS[s0 + 3];
            load_tile<TileR1>(sSt, pb1, st);
            g_rx<0>(st, c0); g_rx<1>(st, c1); g_rx<2>(st, c2); g_rx<3>(st, c3);
            g_cnot<0, 1>(st); g_cnot<1, 2>(st); g_cnot<2, 3>(st);
            store_tile<TileR1>(sSt, pb1, st);
        }
        __syncthreads();
        {   // R2
            cf2 c4 = sCS[s0 + 4], c5 = sCS[s0 + 5], c6 = sCS[s0 + 6];
            load_tile<TileR2>(sSt, pb2, st);
            g_rx<1>(st, c4); g_rx<2>(st, c5); g_rx<3>(st, c6);
            g_cnot<0, 1>(st); g_cnot<1, 2>(st); g_cnot<2, 3>(st);
            store_tile<TileR2>(sSt, pb2, st);
        }
        __syncthreads();
        {   // R3
            cf2 c7 = sCS[s0 + 7], c8 = sCS[s0 + 8], c9 = sCS[s0 + 9];
            load_tile<TileR3>(sSt, pb3, st);
            g_rx<1>(st, c7); g_rx<2>(st, c8); g_rx<3>(st, c9);
            g_cnot<0, 1>(st); g_cnot<1, 2>(st); g_cnot<2, 3>(st);
            store_tile<TileR3>(sSt, pb3, st);
        }
        __syncthreads();
        {   // R4
            cf2 cA = sCS[s0 + 10], cB = sCS[s0 + 11], cC = sCS[s0 + 12];
            load_tile<TileR4>(sSt, pb4, st);
            g_rx<1>(st, cA); g_rx<2>(st, cB); g_rx<3>(st, cC);
            g_cnot<0, 1>(st); g_cnot<1, 2>(st); g_cnot<2, 3>(st);
            store_tile<TileR4>(sSt, pb4, st);
        }
        __syncthreads();
        {   // R5
            cf2 cD = sCS[s0 + 13];
            load_tile<TileR5>(sSt, pb5, st);
            g_rx<1>(st, cD);
            g_cnot<0, 1>(st); g_cnot<1, 2>(st);
            if (l == 1) store_tile<TileR5>(sSt, pb5, st);
        }
        if (l == 1) __syncthreads();
    }

    // ====== expvals from final registers (TileR5: l0=q12,l1=q13,l2=q0,l3=q1) ======
    float Stot = 0.f, S0 = 0.f, S1 = 0.f, S2 = 0.f, S3 = 0.f;
    sfor<TA>([&](auto jc) {
        constexpr int j = decltype(jc)::v;
        cf2 v = amp<j>(st);
        float pj = v.x * v.x + v.y * v.y;
        Stot += pj;
        S0 += (j & 1) ? -pj : pj;   // q12
        S1 += (j & 2) ? -pj : pj;   // q13
        S2 += (j & 4) ? -pj : pj;   // q0
        S3 += (j & 8) ? -pj : pj;   // q1
    });
    float ev[NQ];
    ev[0] = S2; ev[1] = S3; ev[12] = S0; ev[13] = S1;
#pragma unroll
    for (int q = 2; q <= 11; ++q)    // q2..q11 <- tid bit (11-q)
        ev[q] = ((tid >> (11 - q)) & 1) ? -Stot : Stot;

#pragma unroll
    for (int q = 0; q < NQ; ++q) {
#pragma unroll
        for (int o = 32; o > 0; o >>= 1) ev[q] += __shfl_down(ev[q], o);
    }
    const int wv = tid >> 6, ln = tid & 63;
    if (ln == 0) {
#pragma unroll
        for (int q = 0; q < NQ; ++q) sRed[wv][q] = ev[q];
    }
    __syncthreads();
    if (tid < NQ) {
        float acc = 0.f;
#pragma unroll
        for (int k = 0; k < NW; ++k) acc += sRed[k][tid];
        out[b * NQ + tid] = acc;
    }
}

extern "C" void kernel_launch(void* const* d_in, const int* in_sizes, int n_in,
                              void* d_out, int out_size, void* d_ws, size_t ws_size,
                              hipStream_t stream) {
    const float* x = (const float*)d_in[0];   // (256, 14) float32
    const float* w = (const float*)d_in[1];   // (3, 14) float32
    float* out = (float*)d_out;               // (256, 14) float32
    qsim_kernel<<<256, NT, 0, stream>>>(x, w, out);
}

// Round 16
// 79.576 us; speedup vs baseline: 1.0745x; 1.0745x over previous
//
#include <hip/hip_runtime.h>
#include <math.h>

#define NQ 14
#define DIM (1 << NQ)      // 16384 amplitudes
#define NT 512             // 8 waves per block; ~132 KB LDS -> 1 block/CU
#define TA 32              // amplitudes per thread (5-bit tile)
#define NW (NT / 64)
#define PDIM (DIM + DIM / 32)   // padded: one spare cf2 per 32

// ---- compile-time for ----
template <int J> struct IC { static constexpr int v = J; };
template <int N, typename F>
__device__ __forceinline__ void sfor(F&& f) {
    if constexpr (N > 0) { sfor<N - 1>(f); f(IC<N - 1>{}); }
}

// ---- complex amplitude as a 2-wide ext_vector (one 64-bit VGPR pair) ----
typedef float cf2 __attribute__((ext_vector_type(2)));

// ---- packed fp32 gate math (r14-verified; r15-verified (c,s)-pair op_sel
// variants). clang won't lower <2 x float> to v_pk_* — hand asm required. ----
__device__ __forceinline__ cf2 pk_mul_c(cf2 cs, cf2 a) {          // c * a
    cf2 t;
    asm("v_pk_mul_f32 %0, %1, %2 op_sel:[0,0] op_sel_hi:[0,1]"
        : "=v"(t) : "v"(cs), "v"(a));
    return t;
}
__device__ __forceinline__ cf2 pk_mul_s(cf2 cs, cf2 a) {          // s * a
    cf2 t;
    asm("v_pk_mul_f32 %0, %1, %2 op_sel:[1,0] op_sel_hi:[1,1]"
        : "=v"(t) : "v"(cs), "v"(a));
    return t;
}
__device__ __forceinline__ cf2 pk_mul_s_swapneg(cf2 cs, cf2 a) {  // s * (a.y, -a.x)
    cf2 t;
    asm("v_pk_mul_f32 %0, %1, %2 op_sel:[1,1] op_sel_hi:[1,0] neg_hi:[0,1]"
        : "=v"(t) : "v"(cs), "v"(a));
    return t;
}
__device__ __forceinline__ cf2 pk_fma_c(cf2 cs, cf2 a, cf2 b) {   // c*a + b
    cf2 d;
    asm("v_pk_fma_f32 %0, %1, %2, %3 op_sel:[0,0,0] op_sel_hi:[0,1,1]"
        : "=v"(d) : "v"(cs), "v"(a), "v"(b));
    return d;
}
__device__ __forceinline__ cf2 pk_fma_s(cf2 cs, cf2 a, cf2 b) {   // s*a + b
    cf2 d;
    asm("v_pk_fma_f32 %0, %1, %2, %3 op_sel:[1,0,0] op_sel_hi:[1,1,1]"
        : "=v"(d) : "v"(cs), "v"(a), "v"(b));
    return d;
}
__device__ __forceinline__ cf2 pk_fma_c_nb(cf2 cs, cf2 a, cf2 b) { // c*a - b
    cf2 d;
    asm("v_pk_fma_f32 %0, %1, %2, %3 op_sel:[0,0,0] op_sel_hi:[0,1,1] neg_lo:[0,0,1] neg_hi:[0,0,1]"
        : "=v"(d) : "v"(cs), "v"(a), "v"(b));
    return d;
}

// ---- state: 32 INDEPENDENT cf2 SSA values ----
struct St {
    cf2 a0, a1, a2, a3, a4, a5, a6, a7, a8, a9, a10, a11, a12, a13, a14, a15,
        a16, a17, a18, a19, a20, a21, a22, a23, a24, a25, a26, a27, a28, a29, a30, a31;
};
template <int J> __device__ __forceinline__ cf2& amp(St& s);
#define AMP_GET(J) template <> __device__ __forceinline__ cf2& amp<J>(St& s) { return s.a##J; }
AMP_GET(0)  AMP_GET(1)  AMP_GET(2)  AMP_GET(3)  AMP_GET(4)  AMP_GET(5)  AMP_GET(6)  AMP_GET(7)
AMP_GET(8)  AMP_GET(9)  AMP_GET(10) AMP_GET(11) AMP_GET(12) AMP_GET(13) AMP_GET(14) AMP_GET(15)
AMP_GET(16) AMP_GET(17) AMP_GET(18) AMP_GET(19) AMP_GET(20) AMP_GET(21) AMP_GET(22) AMP_GET(23)
AMP_GET(24) AMP_GET(25) AMP_GET(26) AMP_GET(27) AMP_GET(28) AMP_GET(29) AMP_GET(30) AMP_GET(31)

// ---- additive padded layout: phys(idx) = idx + (idx>>5); disjoint-bit sums
// split (a|b -> pad(a)+pad(b)) -> every LDS access = base + const. ----
__host__ __device__ constexpr int pad(int idx) { return idx + (idx >> 5); }

template <int P0, int P1, int P2, int P3, int P4>
struct Tile5 {
    static constexpr int PMASK = (1 << P0) | (1 << P1) | (1 << P2) | (1 << P3) | (1 << P4);
    static __device__ __forceinline__ int base_idx(int t) {
        int idx = 0, tb = 0;
#pragma unroll
        for (int p = 0; p < NQ; ++p)
            if (!((PMASK >> p) & 1)) { idx |= ((t >> tb) & 1) << p; ++tb; }
        return idx;
    }
    static constexpr int off(int j) {
        return ((j & 1) << P0) | (((j >> 1) & 1) << P1) | (((j >> 2) & 1) << P2) |
               (((j >> 3) & 1) << P3) | (((j >> 4) & 1) << P4);
    }
    static constexpr int poff(int j) { return pad(off(j)); }
};

// qubit q lives at bit position 13-q.
// Layer-0 tiles (4 rounds, embedding folded — RY doesn't commute with CNOT target):
using TL1 = Tile5<9, 10, 11, 12, 13>;  // l4..l0 = q0,q1,q2,q3,q4
using TL2 = Tile5<5, 6, 7, 8, 9>;      // l4..l0 = q4,q5,q6,q7,q8
using TL3 = Tile5<1, 2, 3, 4, 5>;      // l4..l0 = q8,q9,q10,q11,q12
using TL4 = Tile5<0, 1, 13, 12, 11>;   // l0=q13, l1=q12, l2=q0, l3=q1, l4=q2
// Layers 1-2 tiles (3 rounds; cross CNOTs folded into loads):
using TT1 = Tile5<9, 10, 11, 12, 13>;  // l4..l0 = q0,q1,q2,q3,q4
using TT2 = Tile5<4, 5, 6, 7, 8>;      // l4..l0 = q5,q6,q7,q8,q9
using TT3 = Tile5<13, 0, 1, 2, 3>;     // l4..l0 = q10,q11,q12,q13,q0

template <class T>
__device__ __forceinline__ void load_tile(const cf2* s, int pb, St& st) {
    sfor<TA>([&](auto jc) {
        constexpr int j = decltype(jc)::v;
        amp<j>(st) = s[pb + T::poff(j)];
    });
}
// Folded load: applies CNOT(ctrl-tid-bit -> target local bit4) during the
// read. Elements with l4=0 read from pbLo(+D if ctrl), l4=1 from pbHi(-D):
// addr = pb + poff(j^16) when ctrl, exploiting pad additivity.
template <class T>
__device__ __forceinline__ void load_tile_fold(const cf2* s, int pbLo, int pbHi, St& st) {
    sfor<TA>([&](auto jc) {
        constexpr int j = decltype(jc)::v;
        amp<j>(st) = s[((j & 16) ? pbHi : pbLo) + T::poff(j)];
    });
}
template <class T>
__device__ __forceinline__ void store_tile(cf2* s, int pb, St& st) {
    sfor<TA>([&](auto jc) {
        constexpr int j = decltype(jc)::v;
        s[pb + T::poff(j)] = amp<j>(st);
    });
}

// RY: [[c,-s],[s,c]]  — cs = (c,s) in one register pair
template <int LB>
__device__ __forceinline__ void g_ry(St& st, cf2 cs) {
    sfor<TA>([&](auto jc) {
        constexpr int j = decltype(jc)::v;
        if constexpr (!(j & (1 << LB))) {
            constexpr int k = j | (1 << LB);
            cf2 aj = amp<j>(st), ak = amp<k>(st);
            amp<j>(st) = pk_fma_c_nb(cs, aj, pk_mul_s(cs, ak));   // c*aj - s*ak
            amp<k>(st) = pk_fma_s(cs, aj, pk_mul_c(cs, ak));      // s*aj + c*ak
        }
    });
}
// RX: [[c,-is],[-is,c]]
template <int LB>
__device__ __forceinline__ void g_rx(St& st, cf2 cs) {
    sfor<TA>([&](auto jc) {
        constexpr int j = decltype(jc)::v;
        if constexpr (!(j & (1 << LB))) {
            constexpr int k = j | (1 << LB);
            cf2 aj = amp<j>(st), ak = amp<k>(st);
            amp<j>(st) = pk_fma_c(cs, aj, pk_mul_s_swapneg(cs, ak));
            amp<k>(st) = pk_fma_c(cs, ak, pk_mul_s_swapneg(cs, aj));
        }
    });
}
// CNOT control local LC, target local LT: pure SSA rename (free)
template <int LC, int LT>
__device__ __forceinline__ void g_cnot(St& st) {
    sfor<TA>([&](auto jc) {
        constexpr int j = decltype(jc)::v;
        if constexpr (((j >> LC) & 1) && !((j >> LT) & 1)) {
            constexpr int k = j | (1 << LT);
            cf2 t = amp<j>(st);
            amp<j>(st) = amp<k>(st);
            amp<k>(st) = t;
        }
    });
}

// Layers 1-2, per layer 3 rounds (validity: RX(t) commutes with CNOT(c,t)
// since RX = c*I - i*s*X; so the cross-tile CNOT whose target is in the next
// tile is applied AT THAT TILE'S LOAD, before its RX):
//  T1 {q0..q4}:  RX q0-4, CNOT(q0,q1)(q1,q2)(q2,q3)(q3,q4)
//  T2 {q5..q9}:  load-fold CNOT(q4,q5) [ctrl=tid bit9], RX q5-9,
//                CNOT(q5,q6)(q6,q7)(q7,q8)(q8,q9)
//  T3 {q10..q13,q0}: load-fold CNOT(q9,q10) [ctrl=tid bit4], RX q10-13,
//                CNOT(q10,q11)(q11,q12)(q12,q13)(q13,q0)  [all in-tile]
__global__ void __launch_bounds__(NT) qsim_kernel(const float* __restrict__ x,
                                                  const float* __restrict__ w,
                                                  float* __restrict__ out) {
    __shared__ cf2 sSt[PDIM];            // ~132 KB padded
    __shared__ cf2 sCS[56];              // (cos,sin): [0..13]=RY embed, 14+l*14+q = RX
    __shared__ float sRed[NW][NQ];

    const int tid = threadIdx.x;
    const int b = blockIdx.x;

    if (tid < 14) {
        float th = tanhf(x[b * NQ + tid]) * 1.57079632679489662f;
        cf2 v; v.x = cosf(th); v.y = sinf(th);
        sCS[tid] = v;
    } else if (tid < 56) {
        float th = w[tid - 14] * 0.5f;
        cf2 v; v.x = cosf(th); v.y = sinf(th);
        sCS[tid] = v;
    }

    const int pbL1 = pad(TL1::base_idx(tid));
    const int pbL2 = pad(TL2::base_idx(tid));
    const int pbL3 = pad(TL3::base_idx(tid));
    const int pbL4 = pad(TL4::base_idx(tid));
    const int pbT2 = pad(TT2::base_idx(tid));
    const int pbT3 = pad(TT3::base_idx(tid));
    // fold bases: T2 target q5 = bit8 -> delta pad(256)=264, ctrl bit9 = tid4
    const int d2 = ((tid >> 4) & 1) ? 264 : 0;
    const int pbT2lo = pbT2 + d2, pbT2hi = pbT2 - d2;
    // T3 target q10 = bit3 -> delta pad(8)=8, ctrl bit4 = tid0
    const int d3 = (tid & 1) ? 8 : 0;
    const int pbT3lo = pbT3 + d3, pbT3hi = pbT3 - d3;

    __syncthreads();

    St st;

    // ================= layer 0 (4 rounds, embedding folded; r14-verified) =================
    {   // R1 {q0..q4}: init + RY q0-4 + RX q0-4 + CNOT(q0,q1)..(q3,q4)
        sfor<TA>([&](auto jc) {
            constexpr int j = decltype(jc)::v;
            cf2 z; z.x = 0.f; z.y = 0.f;
            amp<j>(st) = z;
        });
        if (tid == 0) amp<0>(st).x = 1.f;
        g_ry<0>(st, sCS[4]); g_ry<1>(st, sCS[3]); g_ry<2>(st, sCS[2]);
        g_ry<3>(st, sCS[1]); g_ry<4>(st, sCS[0]);
        g_rx<0>(st, sCS[18]); g_rx<1>(st, sCS[17]); g_rx<2>(st, sCS[16]);
        g_rx<3>(st, sCS[15]); g_rx<4>(st, sCS[14]);
        g_cnot<4, 3>(st); g_cnot<3, 2>(st); g_cnot<2, 1>(st); g_cnot<1, 0>(st);
        store_tile<TL1>(sSt, pbL1, st);
    }
    __syncthreads();
    {   // R2 {q4..q8}: RY q5-8 + RX q5-8 + CNOT(q4,q5)..(q7,q8)
        cf2 y5 = sCS[5], y6 = sCS[6], y7 = sCS[7], y8 = sCS[8];
        cf2 x5 = sCS[19], x6 = sCS[20], x7 = sCS[21], x8 = sCS[22];
        load_tile<TL2>(sSt, pbL2, st);
        g_ry<0>(st, y8); g_ry<1>(st, y7); g_ry<2>(st, y6); g_ry<3>(st, y5);
        g_rx<0>(st, x8); g_rx<1>(st, x7); g_rx<2>(st, x6); g_rx<3>(st, x5);
        g_cnot<4, 3>(st); g_cnot<3, 2>(st); g_cnot<2, 1>(st); g_cnot<1, 0>(st);
        store_tile<TL2>(sSt, pbL2, st);
    }
    __syncthreads();
    {   // R3 {q8..q12}: RY q9-12 + RX q9-12 + CNOT(q8,q9)..(q11,q12)
        cf2 y9 = sCS[9], yA = sCS[10], yB = sCS[11], yC = sCS[12];
        cf2 x9 = sCS[23], xA = sCS[24], xB = sCS[25], xC = sCS[26];
        load_tile<TL3>(sSt, pbL3, st);
        g_ry<0>(st, yC); g_ry<1>(st, yB); g_ry<2>(st, yA); g_ry<3>(st, y9);
        g_rx<0>(st, xC); g_rx<1>(st, xB); g_rx<2>(st, xA); g_rx<3>(st, x9);
        g_cnot<4, 3>(st); g_cnot<3, 2>(st); g_cnot<2, 1>(st); g_cnot<1, 0>(st);
        store_tile<TL3>(sSt, pbL3, st);
    }
    __syncthreads();
    {   // R4 {q13,q12,q0,q1,q2}: RY q13 + RX q13 + CNOT(q12,q13)(q13,q0)
        cf2 yD = sCS[13], xD = sCS[27];
        load_tile<TL4>(sSt, pbL4, st);
        g_ry<0>(st, yD);
        g_rx<0>(st, xD);
        g_cnot<1, 0>(st); g_cnot<0, 2>(st);
        store_tile<TL4>(sSt, pbL4, st);
    }
    __syncthreads();

    // ================= layers 1,2 (3 rounds each) =================
#pragma unroll 1
    for (int l = 1; l < 3; ++l) {
        const int s0 = 14 + l * NQ;
        {   // T1 {q0..q4}
            cf2 c0 = sCS[s0 + 0], c1 = sCS[s0 + 1], c2 = sCS[s0 + 2];
            cf2 c3 = sCS[s0 + 3], c4 = sCS[s0 + 4];
            load_tile<TT1>(sSt, pbL1, st);
            g_rx<0>(st, c4); g_rx<1>(st, c3); g_rx<2>(st, c2);
            g_rx<3>(st, c1); g_rx<4>(st, c0);
            g_cnot<4, 3>(st); g_cnot<3, 2>(st); g_cnot<2, 1>(st); g_cnot<1, 0>(st);
            store_tile<TT1>(sSt, pbL1, st);
        }
        __syncthreads();
        {   // T2 {q5..q9}: load-fold CNOT(q4,q5)
            cf2 c5 = sCS[s0 + 5], c6 = sCS[s0 + 6], c7 = sCS[s0 + 7];
            cf2 c8 = sCS[s0 + 8], c9 = sCS[s0 + 9];
            load_tile_fold<TT2>(sSt, pbT2lo, pbT2hi, st);
            g_rx<0>(st, c9); g_rx<1>(st, c8); g_rx<2>(st, c7);
            g_rx<3>(st, c6); g_rx<4>(st, c5);
            g_cnot<4, 3>(st); g_cnot<3, 2>(st); g_cnot<2, 1>(st); g_cnot<1, 0>(st);
            store_tile<TT2>(sSt, pbT2, st);
        }
        __syncthreads();
        {   // T3 {q10..q13,q0}: load-fold CNOT(q9,q10); (q13,q0) in-tile
            cf2 cA = sCS[s0 + 10], cB = sCS[s0 + 11], cC = sCS[s0 + 12], cD = sCS[s0 + 13];
            load_tile_fold<TT3>(sSt, pbT3lo, pbT3hi, st);
            g_rx<1>(st, cD); g_rx<2>(st, cC); g_rx<3>(st, cB); g_rx<4>(st, cA);
            g_cnot<4, 3>(st); g_cnot<3, 2>(st); g_cnot<2, 1>(st); g_cnot<1, 0>(st);
            if (l == 1) store_tile<TT3>(sSt, pbT3, st);
        }
        if (l == 1) __syncthreads();
    }

    // ====== expvals from final registers (TT3: l0=q0,l1=q13,l2=q12,l3=q11,l4=q10) ======
    float Stot = 0.f, S0 = 0.f, S1 = 0.f, S2 = 0.f, S3 = 0.f, S4 = 0.f;
    sfor<TA>([&](auto jc) {
        constexpr int j = decltype(jc)::v;
        cf2 v = amp<j>(st);
        float pj = v.x * v.x + v.y * v.y;
        Stot += pj;
        S0 += (j & 1)  ? -pj : pj;   // q0
        S1 += (j & 2)  ? -pj : pj;   // q13
        S2 += (j & 4)  ? -pj : pj;   // q12
        S3 += (j & 8)  ? -pj : pj;   // q11
        S4 += (j & 16) ? -pj : pj;   // q10
    });
    float ev[NQ];
    ev[0] = S0; ev[10] = S4; ev[11] = S3; ev[12] = S2; ev[13] = S1;
#pragma unroll
    for (int q = 1; q <= 9; ++q)    // q1..q9 <- tid bit (9-q)  [bit 13-q = tid (9-q)]
        ev[q] = ((tid >> (9 - q)) & 1) ? -Stot : Stot;

#pragma unroll
    for (int q = 0; q < NQ; ++q) {
#pragma unroll
        for (int o = 32; o > 0; o >>= 1) ev[q] += __shfl_down(ev[q], o);
    }
    const int wv = tid >> 6, ln = tid & 63;
    if (ln == 0) {
#pragma unroll
        for (int q = 0; q < NQ; ++q) sRed[wv][q] = ev[q];
    }
    __syncthreads();
    if (tid < NQ) {
        float acc = 0.f;
#pragma unroll
        for (int k = 0; k < NW; ++k) acc += sRed[k][tid];
        out[b * NQ + tid] = acc;
    }
}

extern "C" void kernel_launch(void* const* d_in, const int* in_sizes, int n_in,
                              void* d_out, int out_size, void* d_ws, size_t ws_size,
                              hipStream_t stream) {
    const float* x = (const float*)d_in[0];   // (256, 14) float32
    const float* w = (const float*)d_in[1];   // (3, 14) float32
    float* out = (float*)d_out;               // (256, 14) float32
    qsim_kernel<<<256, NT, 0, stream>>>(x, w, out);
}

// Round 17
// 78.187 us; speedup vs baseline: 1.0935x; 1.0178x over previous
//
#include <hip/hip_runtime.h>
#include <math.h>

#define NQ 14
#define DIM (1 << NQ)      // 16384 amplitudes
#define NT 512             // 8 waves per block; ~132 KB LDS -> 1 block/CU
#define TA 32              // amplitudes per thread (5-bit tile)
#define NW (NT / 64)
#define PDIM (DIM + DIM / 32)   // padded: one spare cf2 per 32

// ---- compile-time for ----
template <int J> struct IC { static constexpr int v = J; };
template <int N, typename F>
__device__ __forceinline__ void sfor(F&& f) {
    if constexpr (N > 0) { sfor<N - 1>(f); f(IC<N - 1>{}); }
}

// ---- complex amplitude as a 2-wide ext_vector (one 64-bit VGPR pair) ----
typedef float cf2 __attribute__((ext_vector_type(2)));

// ---- packed fp32 gate math (r14/r15-verified VOP3P asm; clang won't lower
// <2 x float> to v_pk_*). cs = (cos,sin) in ONE register pair; op_sel
// broadcasts the needed half. ----
__device__ __forceinline__ cf2 pk_mul_c(cf2 cs, cf2 a) {          // c * a
    cf2 t;
    asm("v_pk_mul_f32 %0, %1, %2 op_sel:[0,0] op_sel_hi:[0,1]"
        : "=v"(t) : "v"(cs), "v"(a));
    return t;
}
__device__ __forceinline__ cf2 pk_mul_s(cf2 cs, cf2 a) {          // s * a
    cf2 t;
    asm("v_pk_mul_f32 %0, %1, %2 op_sel:[1,0] op_sel_hi:[1,1]"
        : "=v"(t) : "v"(cs), "v"(a));
    return t;
}
__device__ __forceinline__ cf2 pk_mul_s_swapneg(cf2 cs, cf2 a) {  // s * (a.y, -a.x)
    cf2 t;
    asm("v_pk_mul_f32 %0, %1, %2 op_sel:[1,1] op_sel_hi:[1,0] neg_hi:[0,1]"
        : "=v"(t) : "v"(cs), "v"(a));
    return t;
}
__device__ __forceinline__ cf2 pk_fma_c(cf2 cs, cf2 a, cf2 b) {   // c*a + b
    cf2 d;
    asm("v_pk_fma_f32 %0, %1, %2, %3 op_sel:[0,0,0] op_sel_hi:[0,1,1]"
        : "=v"(d) : "v"(cs), "v"(a), "v"(b));
    return d;
}
__device__ __forceinline__ cf2 pk_fma_s(cf2 cs, cf2 a, cf2 b) {   // s*a + b
    cf2 d;
    asm("v_pk_fma_f32 %0, %1, %2, %3 op_sel:[1,0,0] op_sel_hi:[1,1,1]"
        : "=v"(d) : "v"(cs), "v"(a), "v"(b));
    return d;
}
__device__ __forceinline__ cf2 pk_fma_c_nb(cf2 cs, cf2 a, cf2 b) { // c*a - b
    cf2 d;
    asm("v_pk_fma_f32 %0, %1, %2, %3 op_sel:[0,0,0] op_sel_hi:[0,1,1] neg_lo:[0,0,1] neg_hi:[0,0,1]"
        : "=v"(d) : "v"(cs), "v"(a), "v"(b));
    return d;
}

// ---- state: 32 INDEPENDENT cf2 SSA values ----
struct St {
    cf2 a0, a1, a2, a3, a4, a5, a6, a7, a8, a9, a10, a11, a12, a13, a14, a15,
        a16, a17, a18, a19, a20, a21, a22, a23, a24, a25, a26, a27, a28, a29, a30, a31;
};
template <int J> __device__ __forceinline__ cf2& amp(St& s);
#define AMP_GET(J) template <> __device__ __forceinline__ cf2& amp<J>(St& s) { return s.a##J; }
AMP_GET(0)  AMP_GET(1)  AMP_GET(2)  AMP_GET(3)  AMP_GET(4)  AMP_GET(5)  AMP_GET(6)  AMP_GET(7)
AMP_GET(8)  AMP_GET(9)  AMP_GET(10) AMP_GET(11) AMP_GET(12) AMP_GET(13) AMP_GET(14) AMP_GET(15)
AMP_GET(16) AMP_GET(17) AMP_GET(18) AMP_GET(19) AMP_GET(20) AMP_GET(21) AMP_GET(22) AMP_GET(23)
AMP_GET(24) AMP_GET(25) AMP_GET(26) AMP_GET(27) AMP_GET(28) AMP_GET(29) AMP_GET(30) AMP_GET(31)

// ---- additive padded layout: phys(idx) = idx + (idx>>5); disjoint-bit sums
// split -> every LDS access = base + compile-time const. ----
__host__ __device__ constexpr int pad(int idx) { return idx + (idx >> 5); }

template <int P0, int P1, int P2, int P3, int P4>
struct Tile5 {
    static constexpr int PMASK = (1 << P0) | (1 << P1) | (1 << P2) | (1 << P3) | (1 << P4);
    static __device__ __forceinline__ int base_idx(int t) {
        int idx = 0, tb = 0;
#pragma unroll
        for (int p = 0; p < NQ; ++p)
            if (!((PMASK >> p) & 1)) { idx |= ((t >> tb) & 1) << p; ++tb; }
        return idx;
    }
    static constexpr int off(int j) {
        return ((j & 1) << P0) | (((j >> 1) & 1) << P1) | (((j >> 2) & 1) << P2) |
               (((j >> 3) & 1) << P3) | (((j >> 4) & 1) << P4);
    }
    static constexpr int poff(int j) { return pad(off(j)); }
};

// qubit q lives at bit position 13-q. Three tiles, used by ALL layers now:
using TT1 = Tile5<9, 10, 11, 12, 13>;  // l4..l0 = q0,q1,q2,q3,q4
using TT2 = Tile5<4, 5, 6, 7, 8>;      // l4..l0 = q5,q6,q7,q8,q9
using TT3 = Tile5<13, 0, 1, 2, 3>;     // l4..l0 = q10,q11,q12,q13,q0

template <class T>
__device__ __forceinline__ void load_tile(const cf2* s, int pb, St& st) {
    sfor<TA>([&](auto jc) {
        constexpr int j = decltype(jc)::v;
        amp<j>(st) = s[pb + T::poff(j)];
    });
}
// Folded load (layers 1-2 only; valid because RX(t) commutes with CNOT(c,t)):
// elements with l4=0 read from pbLo, l4=1 from pbHi (bases carry +/-delta
// when the tid ctrl bit is set), exploiting pad additivity.
template <class T>
__device__ __forceinline__ void load_tile_fold(const cf2* s, int pbLo, int pbHi, St& st) {
    sfor<TA>([&](auto jc) {
        constexpr int j = decltype(jc)::v;
        amp<j>(st) = s[((j & 16) ? pbHi : pbLo) + T::poff(j)];
    });
}
template <class T>
__device__ __forceinline__ void store_tile(cf2* s, int pb, St& st) {
    sfor<TA>([&](auto jc) {
        constexpr int j = decltype(jc)::v;
        s[pb + T::poff(j)] = amp<j>(st);
    });
}

// RY: [[c,-s],[s,c]]
template <int LB>
__device__ __forceinline__ void g_ry(St& st, cf2 cs) {
    sfor<TA>([&](auto jc) {
        constexpr int j = decltype(jc)::v;
        if constexpr (!(j & (1 << LB))) {
            constexpr int k = j | (1 << LB);
            cf2 aj = amp<j>(st), ak = amp<k>(st);
            amp<j>(st) = pk_fma_c_nb(cs, aj, pk_mul_s(cs, ak));   // c*aj - s*ak
            amp<k>(st) = pk_fma_s(cs, aj, pk_mul_c(cs, ak));      // s*aj + c*ak
        }
    });
}
// RX: [[c,-is],[-is,c]]
template <int LB>
__device__ __forceinline__ void g_rx(St& st, cf2 cs) {
    sfor<TA>([&](auto jc) {
        constexpr int j = decltype(jc)::v;
        if constexpr (!(j & (1 << LB))) {
            constexpr int k = j | (1 << LB);
            cf2 aj = amp<j>(st), ak = amp<k>(st);
            amp<j>(st) = pk_fma_c(cs, aj, pk_mul_s_swapneg(cs, ak));
            amp<k>(st) = pk_fma_c(cs, ak, pk_mul_s_swapneg(cs, aj));
        }
    });
}
// CNOT both-local: pure SSA rename (free)
template <int LC, int LT>
__device__ __forceinline__ void g_cnot(St& st) {
    sfor<TA>([&](auto jc) {
        constexpr int j = decltype(jc)::v;
        if constexpr (((j >> LC) & 1) && !((j >> LT) & 1)) {
            constexpr int k = j | (1 << LT);
            cf2 t = amp<j>(st);
            amp<j>(st) = amp<k>(st);
            amp<k>(st) = t;
        }
    });
}
// CNOT with ctrl = per-thread (divergent) tid bit, target = local bit LT:
// predicated register swap (~64 v_cndmask). Used in layer 0, where the
// embedding RY blocks the load-fold (RY does NOT commute with CNOT target).
template <int LT>
__device__ __forceinline__ void g_cnot_pred(St& st, bool ctrl) {
    sfor<TA>([&](auto jc) {
        constexpr int j = decltype(jc)::v;
        if constexpr (!((j >> LT) & 1)) {
            constexpr int k = j | (1 << LT);
            cf2 a = amp<j>(st), b = amp<k>(st);
            amp<j>(st) = ctrl ? b : a;
            amp<k>(st) = ctrl ? a : b;
        }
    });
}

// ALL layers now 3 rounds. Ring CNOTs (q0,q1)..(q12,q13)(q13,q0):
//  T1 {q0..q4}:  [RY q0-4 (l0 only)] RX q0-4, CNOT(q0,q1)..(q3,q4) in-tile
//  T2 {q5..q9}:  layer0: RY/RX q5-9 then PRED-CNOT(q4,q5) then chain;
//                layers1-2: load-fold CNOT(q4,q5), RX q5-9, chain (q5,q6)..(q8,q9)
//  T3 {q10-13,q0}: layer0: RY/RX q10-13 then PRED-CNOT(q9,q10) then chain;
//                layers1-2: load-fold CNOT(q9,q10), RX q10-13, chain incl (q13,q0)
__global__ void __launch_bounds__(NT) qsim_kernel(const float* __restrict__ x,
                                                  const float* __restrict__ w,
                                                  float* __restrict__ out) {
    __shared__ cf2 sSt[PDIM];            // ~132 KB padded
    __shared__ cf2 sCS[56];              // (cos,sin): [0..13]=RY embed, 14+l*14+q = RX
    __shared__ float sRed[NW][NQ];

    const int tid = threadIdx.x;
    const int b = blockIdx.x;

    if (tid < 14) {
        float th = tanhf(x[b * NQ + tid]) * 1.57079632679489662f;
        cf2 v; v.x = cosf(th); v.y = sinf(th);
        sCS[tid] = v;
    } else if (tid < 56) {
        float th = w[tid - 14] * 0.5f;
        cf2 v; v.x = cosf(th); v.y = sinf(th);
        sCS[tid] = v;
    }

    const int pbT1 = pad(TT1::base_idx(tid));
    const int pbT2 = pad(TT2::base_idx(tid));
    const int pbT3 = pad(TT3::base_idx(tid));
    // fold bases (layers 1-2): T2 target q5 = bit8 -> delta pad(256)=264, ctrl q4 = tid bit4
    const int d2 = ((tid >> 4) & 1) ? 264 : 0;
    const int pbT2lo = pbT2 + d2, pbT2hi = pbT2 - d2;
    // T3 target q10 = bit3 -> delta pad(8)=8, ctrl q9 = tid bit0
    const int d3 = (tid & 1) ? 8 : 0;
    const int pbT3lo = pbT3 + d3, pbT3hi = pbT3 - d3;

    const bool c45 = (tid >> 4) & 1;   // q4 ctrl for layer0 pred-CNOT
    const bool c9A = tid & 1;          // q9 ctrl for layer0 pred-CNOT

    __syncthreads();

    St st;

    // ================= layer 0 (3 rounds, embedding folded) =================
    {   // T1: init |0..0> + RY q0-4 + RX q0-4 + CNOT(q0,q1)..(q3,q4)
        sfor<TA>([&](auto jc) {
            constexpr int j = decltype(jc)::v;
            cf2 z; z.x = 0.f; z.y = 0.f;
            amp<j>(st) = z;
        });
        if (tid == 0) amp<0>(st).x = 1.f;
        g_ry<0>(st, sCS[4]); g_ry<1>(st, sCS[3]); g_ry<2>(st, sCS[2]);
        g_ry<3>(st, sCS[1]); g_ry<4>(st, sCS[0]);
        g_rx<0>(st, sCS[18]); g_rx<1>(st, sCS[17]); g_rx<2>(st, sCS[16]);
        g_rx<3>(st, sCS[15]); g_rx<4>(st, sCS[14]);
        g_cnot<4, 3>(st); g_cnot<3, 2>(st); g_cnot<2, 1>(st); g_cnot<1, 0>(st);
        store_tile<TT1>(sSt, pbT1, st);
    }
    __syncthreads();
    {   // T2: RY q5-9 + RX q5-9 + pred-CNOT(q4,q5) + chain (q5,q6)..(q8,q9)
        cf2 y5 = sCS[5], y6 = sCS[6], y7 = sCS[7], y8 = sCS[8], y9 = sCS[9];
        cf2 x5 = sCS[19], x6 = sCS[20], x7 = sCS[21], x8 = sCS[22], x9 = sCS[23];
        load_tile<TT2>(sSt, pbT2, st);
        g_ry<0>(st, y9); g_ry<1>(st, y8); g_ry<2>(st, y7); g_ry<3>(st, y6); g_ry<4>(st, y5);
        g_rx<0>(st, x9); g_rx<1>(st, x8); g_rx<2>(st, x7); g_rx<3>(st, x6); g_rx<4>(st, x5);
        g_cnot_pred<4>(st, c45);          // (q4,q5)
        g_cnot<4, 3>(st); g_cnot<3, 2>(st); g_cnot<2, 1>(st); g_cnot<1, 0>(st);
        store_tile<TT2>(sSt, pbT2, st);
    }
    __syncthreads();
    {   // T3: RY q10-13 + RX q10-13 + pred-CNOT(q9,q10) + chain (q10,q11)..(q13,q0)
        cf2 yA = sCS[10], yB = sCS[11], yC = sCS[12], yD = sCS[13];
        cf2 xA = sCS[24], xB = sCS[25], xC = sCS[26], xD = sCS[27];
        load_tile<TT3>(sSt, pbT3, st);
        g_ry<1>(st, yD); g_ry<2>(st, yC); g_ry<3>(st, yB); g_ry<4>(st, yA);
        g_rx<1>(st, xD); g_rx<2>(st, xC); g_rx<3>(st, xB); g_rx<4>(st, xA);
        g_cnot_pred<4>(st, c9A);          // (q9,q10)
        g_cnot<4, 3>(st); g_cnot<3, 2>(st); g_cnot<2, 1>(st); g_cnot<1, 0>(st);
        store_tile<TT3>(sSt, pbT3, st);
    }
    __syncthreads();

    // ================= layers 1,2 (3 rounds each; r16-verified) =================
#pragma unroll 1
    for (int l = 1; l < 3; ++l) {
        const int s0 = 14 + l * NQ;
        {   // T1 {q0..q4}
            cf2 c0 = sCS[s0 + 0], c1 = sCS[s0 + 1], c2 = sCS[s0 + 2];
            cf2 c3 = sCS[s0 + 3], c4 = sCS[s0 + 4];
            load_tile<TT1>(sSt, pbT1, st);
            g_rx<0>(st, c4); g_rx<1>(st, c3); g_rx<2>(st, c2);
            g_rx<3>(st, c1); g_rx<4>(st, c0);
            g_cnot<4, 3>(st); g_cnot<3, 2>(st); g_cnot<2, 1>(st); g_cnot<1, 0>(st);
            store_tile<TT1>(sSt, pbT1, st);
        }
        __syncthreads();
        {   // T2 {q5..q9}: load-fold CNOT(q4,q5)
            cf2 c5 = sCS[s0 + 5], c6 = sCS[s0 + 6], c7 = sCS[s0 + 7];
            cf2 c8 = sCS[s0 + 8], c9 = sCS[s0 + 9];
            load_tile_fold<TT2>(sSt, pbT2lo, pbT2hi, st);
            g_rx<0>(st, c9); g_rx<1>(st, c8); g_rx<2>(st, c7);
            g_rx<3>(st, c6); g_rx<4>(st, c5);
            g_cnot<4, 3>(st); g_cnot<3, 2>(st); g_cnot<2, 1>(st); g_cnot<1, 0>(st);
            store_tile<TT2>(sSt, pbT2, st);
        }
        __syncthreads();
        {   // T3 {q10..q13,q0}: load-fold CNOT(q9,q10); (q13,q0) in-tile
            cf2 cA = sCS[s0 + 10], cB = sCS[s0 + 11], cC = sCS[s0 + 12], cD = sCS[s0 + 13];
            load_tile_fold<TT3>(sSt, pbT3lo, pbT3hi, st);
            g_rx<1>(st, cD); g_rx<2>(st, cC); g_rx<3>(st, cB); g_rx<4>(st, cA);
            g_cnot<4, 3>(st); g_cnot<3, 2>(st); g_cnot<2, 1>(st); g_cnot<1, 0>(st);
            if (l == 1) store_tile<TT3>(sSt, pbT3, st);
        }
        if (l == 1) __syncthreads();
    }

    // ====== expvals from final registers (TT3: l0=q0,l1=q13,l2=q12,l3=q11,l4=q10) ======
    float Stot = 0.f, S0 = 0.f, S1 = 0.f, S2 = 0.f, S3 = 0.f, S4 = 0.f;
    sfor<TA>([&](auto jc) {
        constexpr int j = decltype(jc)::v;
        cf2 v = amp<j>(st);
        float pj = v.x * v.x + v.y * v.y;
        Stot += pj;
        S0 += (j & 1)  ? -pj : pj;   // q0
        S1 += (j & 2)  ? -pj : pj;   // q13
        S2 += (j & 4)  ? -pj : pj;   // q12
        S3 += (j & 8)  ? -pj : pj;   // q11
        S4 += (j & 16) ? -pj : pj;   // q10
    });
    float ev[NQ];
    ev[0] = S0; ev[10] = S4; ev[11] = S3; ev[12] = S2; ev[13] = S1;
#pragma unroll
    for (int q = 1; q <= 9; ++q)    // q1..q9 <- tid bit (9-q)
        ev[q] = ((tid >> (9 - q)) & 1) ? -Stot : Stot;

#pragma unroll
    for (int q = 0; q < NQ; ++q) {
#pragma unroll
        for (int o = 32; o > 0; o >>= 1) ev[q] += __shfl_down(ev[q], o);
    }
    const int wv = tid >> 6, ln = tid & 63;
    if (ln == 0) {
#pragma unroll
        for (int q = 0; q < NQ; ++q) sRed[wv][q] = ev[q];
    }
    __syncthreads();
    if (tid < NQ) {
        float acc = 0.f;
#pragma unroll
        for (int k = 0; k < NW; ++k) acc += sRed[k][tid];
        out[b * NQ + tid] = acc;
    }
}

extern "C" void kernel_launch(void* const* d_in, const int* in_sizes, int n_in,
                              void* d_out, int out_size, void* d_ws, size_t ws_size,
                              hipStream_t stream) {
    const float* x = (const float*)d_in[0];   // (256, 14) float32
    const float* w = (const float*)d_in[1];   // (3, 14) float32
    float* out = (float*)d_out;               // (256, 14) float32
    qsim_kernel<<<256, NT, 0, stream>>>(x, w, out);
}